// Round 1
// baseline (355.403 us; speedup 1.0000x reference)
//
#include <hip/hip_runtime.h>
#include <math.h>

#define HW 16384
#define Wd 128

// ---------------- K1: per (b,c) spatial mean ----------------
__global__ void k_mean(const float* __restrict__ x, float* __restrict__ xmean) {
  int bc = blockIdx.x;                       // 0..95  (b*48+c)
  const float* p = x + (size_t)bc * HW;
  float s = 0.f;
  for (int i = threadIdx.x; i < HW; i += 256) s += p[i];
  #pragma unroll
  for (int off = 32; off > 0; off >>= 1) s += __shfl_down(s, off, 64);
  __shared__ float wsum[4];
  int lane = threadIdx.x & 63, wv = threadIdx.x >> 6;
  if (lane == 0) wsum[wv] = s;
  __syncthreads();
  if (threadIdx.x == 0)
    xmean[bc] = (wsum[0] + wsum[1] + wsum[2] + wsum[3]) * (1.f / 16384.f);
}

// ---------------- K2: sca = 1x1(xmean) ----------------
__global__ void k_sca(const float* __restrict__ xmean, const float* __restrict__ w_sca,
                      const float* __restrict__ b_sca, float* __restrict__ sca) {
  int t = threadIdx.x;
  if (t < 192) {
    int b = t / 96, co = t % 96;
    float acc = b_sca[co];
    for (int ci = 0; ci < 48; ci++) acc += w_sca[co * 48 + ci] * xmean[b * 48 + ci];
    sca[t] = acc;
  }
}

// ---------------- K3: two 1x1 convs 48->96 (h_a, h_c) ----------------
// 64 px per block; wave w handles out-channels [24w, 24w+24)
__global__ void k_pw1(const float* __restrict__ x,
                      const float* __restrict__ w1a, const float* __restrict__ b1a,
                      const float* __restrict__ w1c, const float* __restrict__ b1c,
                      float* __restrict__ ha, float* __restrict__ hc) {
  int lane = threadIdx.x & 63;
  int wv = __builtin_amdgcn_readfirstlane((int)(threadIdx.x >> 6));
  int p = blockIdx.x * 64 + lane;
  int b = p >> 14, sp = p & (HW - 1);
  const float* xb = x + (size_t)b * 48 * HW + sp;
  float xv[48];
  #pragma unroll
  for (int ci = 0; ci < 48; ci++) xv[ci] = xb[(size_t)ci * HW];
  float* hab = ha + (size_t)b * 96 * HW + sp;
  float* hcb = hc + (size_t)b * 96 * HW + sp;
  int c0 = wv * 24;
  for (int co = c0; co < c0 + 24; co++) {
    float aa = b1a[co], ac = b1c[co];
    const float* wa = w1a + co * 48;
    const float* wc = w1c + co * 48;
    #pragma unroll
    for (int ci = 0; ci < 48; ci++) { aa += wa[ci] * xv[ci]; ac += wc[ci] * xv[ci]; }
    hab[(size_t)co * HW] = aa;
    hcb[(size_t)co * HW] = ac;
  }
}

// ---------------- K4: depthwise 3x3 on h_a -> x1 (pre-gelu), h_c -> uf ----------------
__global__ void k_dw(const float* __restrict__ ha, const float* __restrict__ hc,
                     const float* __restrict__ wdwa, const float* __restrict__ bdwa,
                     const float* __restrict__ wdwc, const float* __restrict__ bdwc,
                     float* __restrict__ x1, float* __restrict__ uf) {
  int idx = blockIdx.x * 256 + threadIdx.x;        // < B*96*HW
  int sp = idx & (HW - 1);
  int bc = idx >> 14;                              // b*96+ch
  int ch = bc % 96;
  int r = sp >> 7, c = sp & 127;
  const float* pa = ha + (size_t)bc * HW;
  const float* pc = hc + (size_t)bc * HW;
  float aa = bdwa[ch], ac = bdwc[ch];
  #pragma unroll
  for (int t9 = 0; t9 < 9; t9++) {
    int rr = r + t9 / 3 - 1, cc = c + t9 % 3 - 1;
    bool ok = ((unsigned)rr < 128u) && ((unsigned)cc < 128u);
    float va = ok ? pa[rr * Wd + cc] : 0.f;
    float vc = ok ? pc[rr * Wd + cc] : 0.f;
    float wa = wdwa[ch * 9 + t9], wc = wdwc[ch * 9 + t9];
    aa += wa * va;
    ac += wc * vc;
  }
  x1[idx] = aa;
  uf[idx] = ac;
}

// ---------------- K5: att = 1x1(gate(grouped3x3(x)))*gamma + 1x1(x) ----------------
// 64 px per block; wave w handles att channels [8w, 8w+8)
__global__ void k_att(const float* __restrict__ x,
                      const float* __restrict__ wc2a, const float* __restrict__ bc2a,
                      const float* __restrict__ wc2b, const float* __restrict__ bc2b,
                      const float* __restrict__ w211, const float* __restrict__ b211,
                      const float* __restrict__ attg, float* __restrict__ att) {
  int lane = threadIdx.x & 63;
  int wv = __builtin_amdgcn_readfirstlane((int)(threadIdx.x >> 6));
  int p = blockIdx.x * 64 + lane;
  int b = p >> 14, sp = p & (HW - 1);
  int r = sp >> 7, c = sp & 127;
  const float* xb = x + (size_t)b * 48 * HW;
  float m[12];
  {
    float t[24];
    for (int o = 0; o < 24; o++) {
      float acc = bc2a[o];
      #pragma unroll
      for (int ic = 0; ic < 2; ic++) {
        const float* xc = xb + (size_t)(2 * o + ic) * HW;
        const float* wo = wc2a + o * 18 + ic * 9;
        #pragma unroll
        for (int t9 = 0; t9 < 9; t9++) {
          int rr = r + t9 / 3 - 1, cc = c + t9 % 3 - 1;
          float v = (((unsigned)rr < 128u) && ((unsigned)cc < 128u)) ? xc[rr * Wd + cc] : 0.f;
          acc += wo[t9] * v;
        }
      }
      t[o] = acc;
    }
    #pragma unroll
    for (int i = 0; i < 12; i++) m[i] = t[i] * t[i + 12];
  }
  float xv[48];
  #pragma unroll
  for (int ci = 0; ci < 48; ci++) xv[ci] = xb[(size_t)ci * HW + sp];
  float* ab = att + (size_t)b * 32 * HW + sp;
  int n0 = wv * 8;
  for (int n = n0; n < n0 + 8; n++) {
    float a1 = bc2b[n];
    #pragma unroll
    for (int i = 0; i < 12; i++) a1 += wc2b[n * 12 + i] * m[i];
    float a2 = b211[n];
    #pragma unroll
    for (int ci = 0; ci < 48; ci++) a2 += w211[n * 48 + ci] * xv[ci];
    ab[(size_t)n * HW] = a1 * attg[n] + a2;
  }
}

// ---------------- K6: fused kba + bias + ga1 + uf + gelu(x1) + sca -> y ----------------
// 64 px per block, 4 waves; wave w handles groups [12w, 12w+12).
// kb_w/kb_b addressing is wave-uniform -> scalar loads on SALU pipe.
__global__ __launch_bounds__(256) void k_kba(
    const float* __restrict__ uf, const float* __restrict__ x1,
    const float* __restrict__ att, const float* __restrict__ kbw,
    const float* __restrict__ kbb, const float* __restrict__ ga1,
    const float* __restrict__ sca, float* __restrict__ y) {
  __shared__ float att_s[64][33];               // +1 pad: conflict-free
  int tid = threadIdx.x;
  int lane = tid & 63;
  int wv = __builtin_amdgcn_readfirstlane(tid >> 6);
  int p0 = blockIdx.x * 64;
  int b = p0 >> 14, sp0 = p0 & (HW - 1);
  const float* ab = att + (size_t)b * 32 * HW + sp0;
  for (int i = tid; i < 64 * 32; i += 256) {
    int px = i & 63, n = i >> 6;
    att_s[px][n] = ab[(size_t)n * HW + px];
  }
  __syncthreads();

  int sp = sp0 + lane;
  int r = sp >> 7, cc = sp & 127;
  int noff[9];
  bool nok[9];
  #pragma unroll
  for (int t9 = 0; t9 < 9; t9++) {
    int rr = r + t9 / 3 - 1, c2 = cc + t9 % 3 - 1;
    nok[t9] = ((unsigned)rr < 128u) && ((unsigned)c2 < 128u);
    noff[t9] = rr * Wd + c2;
  }
  const float* ufb = uf + (size_t)b * 96 * HW;
  const float* x1b = x1 + (size_t)b * 96 * HW;
  float* yb = y + (size_t)b * 96 * HW;

  for (int gg = 0; gg < 12; gg++) {
    int g = wv * 12 + gg;
    int c0 = 2 * g;
    const float* u0 = ufb + (size_t)c0 * HW;
    const float* u1 = u0 + HW;
    float P[18];
    #pragma unroll
    for (int t9 = 0; t9 < 9; t9++) {
      P[t9]     = nok[t9] ? u0[noff[t9]] : 0.f;
      P[9 + t9] = nok[t9] ? u1[noff[t9]] : 0.f;
    }
    float acc0 = 0.f, acc1 = 0.f;
    for (int n = 0; n < 32; n++) {
      const float* kw = kbw + n * 1728 + g * 36;   // wave-uniform
      float q0 = kbb[n * 96 + c0];                 // bias folded into dot
      float q1 = kbb[n * 96 + c0 + 1];
      #pragma unroll
      for (int j = 0; j < 18; j++) {
        q0 += kw[j]      * P[j];
        q1 += kw[18 + j] * P[j];
      }
      float a = att_s[lane][n];
      acc0 += a * q0;
      acc1 += a * q1;
    }
    float x2_0 = acc0 * ga1[c0]     + P[4];        // center tap = uf
    float x2_1 = acc1 * ga1[c0 + 1] + P[13];
    float v0 = x1b[(size_t)c0 * HW + sp];
    float v1 = x1b[(size_t)(c0 + 1) * HW + sp];
    float g0 = v0 * 0.5f * (1.f + erff(v0 * 0.70710678118654752440f));
    float g1 = v1 * 0.5f * (1.f + erff(v1 * 0.70710678118654752440f));
    float s0 = sca[b * 96 + c0], s1 = sca[b * 96 + c0 + 1];
    yb[(size_t)c0 * HW + sp]       = g0 * x2_0 * s0;
    yb[(size_t)(c0 + 1) * HW + sp] = g1 * x2_1 * s1;
  }
}

// ---------------- K7: project_out 96->48 ----------------
__global__ void k_proj(const float* __restrict__ y, const float* __restrict__ wproj,
                       const float* __restrict__ bproj, float* __restrict__ out) {
  int lane = threadIdx.x & 63;
  int wv = __builtin_amdgcn_readfirstlane((int)(threadIdx.x >> 6));
  int p = blockIdx.x * 64 + lane;
  int b = p >> 14, sp = p & (HW - 1);
  const float* yb = y + (size_t)b * 96 * HW + sp;
  float yv[96];
  #pragma unroll
  for (int c = 0; c < 96; c++) yv[c] = yb[(size_t)c * HW];
  float* ob = out + (size_t)b * 48 * HW + sp;
  int co0 = wv * 12;
  for (int co = co0; co < co0 + 12; co++) {
    float acc = bproj[co];
    const float* w = wproj + co * 96;
    #pragma unroll
    for (int c = 0; c < 96; c++) acc += w[c] * yv[c];
    ob[(size_t)co * HW] = acc;
  }
}

extern "C" void kernel_launch(void* const* d_in, const int* in_sizes, int n_in,
                              void* d_out, int out_size, void* d_ws, size_t ws_size,
                              hipStream_t stream) {
  const float* x    = (const float*)d_in[0];
  const float* w1a  = (const float*)d_in[1];
  const float* b1a  = (const float*)d_in[2];
  const float* wdwa = (const float*)d_in[3];
  const float* bdwa = (const float*)d_in[4];
  const float* w1c  = (const float*)d_in[5];
  const float* b1c  = (const float*)d_in[6];
  const float* wdwc = (const float*)d_in[7];
  const float* bdwc = (const float*)d_in[8];
  const float* wsca = (const float*)d_in[9];
  const float* bsca = (const float*)d_in[10];
  const float* wc2a = (const float*)d_in[11];
  const float* bc2a = (const float*)d_in[12];
  const float* wc2b = (const float*)d_in[13];
  const float* bc2b = (const float*)d_in[14];
  const float* w211 = (const float*)d_in[15];
  const float* b211 = (const float*)d_in[16];
  const float* wproj= (const float*)d_in[17];
  const float* bproj= (const float*)d_in[18];
  const float* kbw  = (const float*)d_in[19];
  const float* kbb  = (const float*)d_in[20];
  const float* attg = (const float*)d_in[21];
  const float* ga1  = (const float*)d_in[22];
  float* out = (float*)d_out;

  float* ws    = (float*)d_ws;
  float* xmean = ws;                 // 96
  float* sca   = ws + 96;            // 192
  float* ha    = ws + 288;           // 3145728
  float* hc    = ha + 3145728;       // 3145728
  float* x1    = hc + 3145728;       // 3145728
  float* uf    = x1 + 3145728;       // 3145728
  float* att   = uf + 3145728;       // 1048576
  float* y     = ha;                 // reuse: ha dead after k_dw

  k_mean<<<96, 256, 0, stream>>>(x, xmean);
  k_sca <<<1, 256, 0, stream>>>(xmean, wsca, bsca, sca);
  k_pw1 <<<512, 256, 0, stream>>>(x, w1a, b1a, w1c, b1c, ha, hc);
  k_dw  <<<12288, 256, 0, stream>>>(ha, hc, wdwa, bdwa, wdwc, bdwc, x1, uf);
  k_att <<<512, 256, 0, stream>>>(x, wc2a, bc2a, wc2b, bc2b, w211, b211, attg, att);
  k_kba <<<512, 256, 0, stream>>>(uf, x1, att, kbw, kbb, ga1, sca, y);
  k_proj<<<512, 256, 0, stream>>>(y, wproj, bproj, out);
}

// Round 2
// 202.818 us; speedup vs baseline: 1.7523x; 1.7523x over previous
//
#include <hip/hip_runtime.h>
#include <math.h>

#define HW 16384
#define Wd 128

// ---------------- K1: per (b,c) spatial mean + sca 1x1 fused ----------------
__global__ void k_mean(const float* __restrict__ x, float* __restrict__ xmean) {
  int bc = blockIdx.x;                       // 0..95  (b*48+c)
  const float* p = x + (size_t)bc * HW;
  float s = 0.f;
  for (int i = threadIdx.x; i < HW; i += 256) s += p[i];
  #pragma unroll
  for (int off = 32; off > 0; off >>= 1) s += __shfl_down(s, off, 64);
  __shared__ float wsum[4];
  int lane = threadIdx.x & 63, wv = threadIdx.x >> 6;
  if (lane == 0) wsum[wv] = s;
  __syncthreads();
  if (threadIdx.x == 0)
    xmean[bc] = (wsum[0] + wsum[1] + wsum[2] + wsum[3]) * (1.f / 16384.f);
}

__global__ void k_sca(const float* __restrict__ xmean, const float* __restrict__ w_sca,
                      const float* __restrict__ b_sca, float* __restrict__ sca) {
  int t = threadIdx.x;
  if (t < 192) {
    int b = t / 96, co = t % 96;
    float acc = b_sca[co];
    for (int ci = 0; ci < 48; ci++) acc += w_sca[co * 48 + ci] * xmean[b * 48 + ci];
    sca[t] = acc;
  }
}

// ---------------- K3: two 1x1 convs 48->96 (h_a, h_c) ----------------
// grid (512, 2): 64 px per block; wave-slot (y*4+wv) handles 12 out-channels
__global__ void k_pw1(const float* __restrict__ x,
                      const float* __restrict__ w1a, const float* __restrict__ b1a,
                      const float* __restrict__ w1c, const float* __restrict__ b1c,
                      float* __restrict__ ha, float* __restrict__ hc) {
  int lane = threadIdx.x & 63;
  int wv = __builtin_amdgcn_readfirstlane((int)(threadIdx.x >> 6));
  int slot = __builtin_amdgcn_readfirstlane((int)(blockIdx.y * 4 + wv));
  int p = blockIdx.x * 64 + lane;
  int b = p >> 14, sp = p & (HW - 1);
  const float* xb = x + (size_t)b * 48 * HW + sp;
  float xv[48];
  #pragma unroll
  for (int ci = 0; ci < 48; ci++) xv[ci] = xb[(size_t)ci * HW];
  float* hab = ha + (size_t)b * 96 * HW + sp;
  float* hcb = hc + (size_t)b * 96 * HW + sp;
  int c0 = slot * 12;
  for (int co = c0; co < c0 + 12; co++) {
    float aa = b1a[co], ac = b1c[co];
    const float* wa = w1a + co * 48;
    const float* wc = w1c + co * 48;
    #pragma unroll
    for (int ci = 0; ci < 48; ci++) { aa += wa[ci] * xv[ci]; ac += wc[ci] * xv[ci]; }
    hab[(size_t)co * HW] = aa;
    hcb[(size_t)co * HW] = ac;
  }
}

// ---------------- K4: depthwise 3x3 on h_a -> x1 (pre-gelu), h_c -> uf ----------------
__global__ void k_dw(const float* __restrict__ ha, const float* __restrict__ hc,
                     const float* __restrict__ wdwa, const float* __restrict__ bdwa,
                     const float* __restrict__ wdwc, const float* __restrict__ bdwc,
                     float* __restrict__ x1, float* __restrict__ uf) {
  int idx = blockIdx.x * 256 + threadIdx.x;        // < B*96*HW
  int sp = idx & (HW - 1);
  int bc = idx >> 14;                              // b*96+ch
  int ch = bc % 96;
  int r = sp >> 7, c = sp & 127;
  const float* pa = ha + (size_t)bc * HW;
  const float* pc = hc + (size_t)bc * HW;
  float aa = bdwa[ch], ac = bdwc[ch];
  #pragma unroll
  for (int t9 = 0; t9 < 9; t9++) {
    int rr = r + t9 / 3 - 1, cc = c + t9 % 3 - 1;
    bool ok = ((unsigned)rr < 128u) && ((unsigned)cc < 128u);
    float va = ok ? pa[rr * Wd + cc] : 0.f;
    float vc = ok ? pc[rr * Wd + cc] : 0.f;
    float wa = wdwa[ch * 9 + t9], wc = wdwc[ch * 9 + t9];
    aa += wa * va;
    ac += wc * vc;
  }
  x1[idx] = aa;
  uf[idx] = ac;
}

// ---------------- K5: att = 1x1(gate(grouped3x3(x)))*gamma + 1x1(x) ----------------
// grid (512, 2): 64 px per block; wave-slot handles 4 att channels
__global__ void k_att(const float* __restrict__ x,
                      const float* __restrict__ wc2a, const float* __restrict__ bc2a,
                      const float* __restrict__ wc2b, const float* __restrict__ bc2b,
                      const float* __restrict__ w211, const float* __restrict__ b211,
                      const float* __restrict__ attg, float* __restrict__ att) {
  int lane = threadIdx.x & 63;
  int wv = __builtin_amdgcn_readfirstlane((int)(threadIdx.x >> 6));
  int slot = __builtin_amdgcn_readfirstlane((int)(blockIdx.y * 4 + wv));
  int p = blockIdx.x * 64 + lane;
  int b = p >> 14, sp = p & (HW - 1);
  int r = sp >> 7, c = sp & 127;
  const float* xb = x + (size_t)b * 48 * HW;
  float m[12];
  {
    float t[24];
    for (int o = 0; o < 24; o++) {
      float acc = bc2a[o];
      #pragma unroll
      for (int ic = 0; ic < 2; ic++) {
        const float* xc = xb + (size_t)(2 * o + ic) * HW;
        const float* wo = wc2a + o * 18 + ic * 9;
        #pragma unroll
        for (int t9 = 0; t9 < 9; t9++) {
          int rr = r + t9 / 3 - 1, cc = c + t9 % 3 - 1;
          float v = (((unsigned)rr < 128u) && ((unsigned)cc < 128u)) ? xc[rr * Wd + cc] : 0.f;
          acc += wo[t9] * v;
        }
      }
      t[o] = acc;
    }
    #pragma unroll
    for (int i = 0; i < 12; i++) m[i] = t[i] * t[i + 12];
  }
  float xv[48];
  #pragma unroll
  for (int ci = 0; ci < 48; ci++) xv[ci] = xb[(size_t)ci * HW + sp];
  float* ab = att + (size_t)b * 32 * HW + sp;
  int n0 = slot * 4;
  for (int n = n0; n < n0 + 4; n++) {
    float a1 = bc2b[n];
    #pragma unroll
    for (int i = 0; i < 12; i++) a1 += wc2b[n * 12 + i] * m[i];
    float a2 = b211[n];
    #pragma unroll
    for (int ci = 0; ci < 48; ci++) a2 += w211[n * 48 + ci] * xv[ci];
    ab[(size_t)n * HW] = a1 * attg[n] + a2;
  }
}

// ---------------- K6: fused kba + bias + ga1 + uf + gelu(x1) + sca -> y ----------------
// grid (512, 4): 64 px per block; wave wv owns groups [y*12 + wv*3, +3)
// processed CONCURRENTLY in the n-loop (6 independent acc chains).
__global__ __launch_bounds__(256) void k_kba(
    const float* __restrict__ uf, const float* __restrict__ x1,
    const float* __restrict__ att, const float* __restrict__ kbw,
    const float* __restrict__ kbb, const float* __restrict__ ga1,
    const float* __restrict__ sca, float* __restrict__ y) {
  __shared__ float att_s[64][33];               // +1 pad: conflict-free
  int tid = threadIdx.x;
  int lane = tid & 63;
  int wv = __builtin_amdgcn_readfirstlane(tid >> 6);
  int g0 = __builtin_amdgcn_readfirstlane((int)(blockIdx.y * 12 + wv * 3));
  int p0 = blockIdx.x * 64;
  int b = p0 >> 14, sp0 = p0 & (HW - 1);
  const float* ab = att + (size_t)b * 32 * HW + sp0;
  for (int i = tid; i < 64 * 32; i += 256) {
    int px = i & 63, n = i >> 6;
    att_s[px][n] = ab[(size_t)n * HW + px];
  }
  __syncthreads();

  int sp = sp0 + lane;
  int r = sp >> 7, cc = sp & 127;
  int noff[9];
  bool nok[9];
  #pragma unroll
  for (int t9 = 0; t9 < 9; t9++) {
    int rr = r + t9 / 3 - 1, c2 = cc + t9 % 3 - 1;
    nok[t9] = ((unsigned)rr < 128u) && ((unsigned)c2 < 128u);
    noff[t9] = rr * Wd + c2;
  }
  const float* ufb = uf + (size_t)b * 96 * HW;
  const float* x1b = x1 + (size_t)b * 96 * HW;
  float* yb = y + (size_t)b * 96 * HW;

  float P[3][18];
  #pragma unroll
  for (int gg = 0; gg < 3; gg++) {
    const float* u0 = ufb + (size_t)(2 * (g0 + gg)) * HW;
    const float* u1 = u0 + HW;
    #pragma unroll
    for (int t9 = 0; t9 < 9; t9++) {
      P[gg][t9]     = nok[t9] ? u0[noff[t9]] : 0.f;
      P[gg][9 + t9] = nok[t9] ? u1[noff[t9]] : 0.f;
    }
  }
  float acc[3][2] = {{0.f, 0.f}, {0.f, 0.f}, {0.f, 0.f}};
  for (int n = 0; n < 32; n++) {
    float a = att_s[lane][n];
    #pragma unroll
    for (int gg = 0; gg < 3; gg++) {
      int g = g0 + gg;
      const float* kw = kbw + n * 1728 + g * 36;   // wave-uniform -> scalar loads
      float q0 = kbb[n * 96 + 2 * g];
      float q1 = kbb[n * 96 + 2 * g + 1];
      #pragma unroll
      for (int j = 0; j < 18; j++) {
        q0 += kw[j]      * P[gg][j];
        q1 += kw[18 + j] * P[gg][j];
      }
      acc[gg][0] += a * q0;
      acc[gg][1] += a * q1;
    }
  }
  #pragma unroll
  for (int gg = 0; gg < 3; gg++) {
    int c0 = 2 * (g0 + gg);
    float x2_0 = acc[gg][0] * ga1[c0]     + P[gg][4];   // center tap = uf
    float x2_1 = acc[gg][1] * ga1[c0 + 1] + P[gg][13];
    float v0 = x1b[(size_t)c0 * HW + sp];
    float v1 = x1b[(size_t)(c0 + 1) * HW + sp];
    float gl0 = v0 * 0.5f * (1.f + erff(v0 * 0.70710678118654752440f));
    float gl1 = v1 * 0.5f * (1.f + erff(v1 * 0.70710678118654752440f));
    float s0 = sca[b * 96 + c0], s1 = sca[b * 96 + c0 + 1];
    yb[(size_t)c0 * HW + sp]       = gl0 * x2_0 * s0;
    yb[(size_t)(c0 + 1) * HW + sp] = gl1 * x2_1 * s1;
  }
}

// ---------------- K7: project_out 96->48 ----------------
// grid (512, 2): wave-slot handles 6 out-channels
__global__ void k_proj(const float* __restrict__ y, const float* __restrict__ wproj,
                       const float* __restrict__ bproj, float* __restrict__ out) {
  int lane = threadIdx.x & 63;
  int wv = __builtin_amdgcn_readfirstlane((int)(threadIdx.x >> 6));
  int slot = __builtin_amdgcn_readfirstlane((int)(blockIdx.y * 4 + wv));
  int p = blockIdx.x * 64 + lane;
  int b = p >> 14, sp = p & (HW - 1);
  const float* yb = y + (size_t)b * 96 * HW + sp;
  float yv[96];
  #pragma unroll
  for (int c = 0; c < 96; c++) yv[c] = yb[(size_t)c * HW];
  float* ob = out + (size_t)b * 48 * HW + sp;
  int co0 = slot * 6;
  for (int co = co0; co < co0 + 6; co++) {
    float acc = bproj[co];
    const float* w = wproj + co * 96;
    #pragma unroll
    for (int c = 0; c < 96; c++) acc += w[c] * yv[c];
    ob[(size_t)co * HW] = acc;
  }
}

extern "C" void kernel_launch(void* const* d_in, const int* in_sizes, int n_in,
                              void* d_out, int out_size, void* d_ws, size_t ws_size,
                              hipStream_t stream) {
  const float* x    = (const float*)d_in[0];
  const float* w1a  = (const float*)d_in[1];
  const float* b1a  = (const float*)d_in[2];
  const float* wdwa = (const float*)d_in[3];
  const float* bdwa = (const float*)d_in[4];
  const float* w1c  = (const float*)d_in[5];
  const float* b1c  = (const float*)d_in[6];
  const float* wdwc = (const float*)d_in[7];
  const float* bdwc = (const float*)d_in[8];
  const float* wsca = (const float*)d_in[9];
  const float* bsca = (const float*)d_in[10];
  const float* wc2a = (const float*)d_in[11];
  const float* bc2a = (const float*)d_in[12];
  const float* wc2b = (const float*)d_in[13];
  const float* bc2b = (const float*)d_in[14];
  const float* w211 = (const float*)d_in[15];
  const float* b211 = (const float*)d_in[16];
  const float* wproj= (const float*)d_in[17];
  const float* bproj= (const float*)d_in[18];
  const float* kbw  = (const float*)d_in[19];
  const float* kbb  = (const float*)d_in[20];
  const float* attg = (const float*)d_in[21];
  const float* ga1  = (const float*)d_in[22];
  float* out = (float*)d_out;

  float* ws    = (float*)d_ws;
  float* xmean = ws;                 // 96
  float* sca   = ws + 96;            // 192
  float* ha    = ws + 288;           // 3145728
  float* hc    = ha + 3145728;       // 3145728
  float* x1    = hc + 3145728;       // 3145728
  float* uf    = x1 + 3145728;       // 3145728
  float* att   = uf + 3145728;       // 1048576
  float* y     = ha;                 // reuse: ha dead after k_dw

  k_mean<<<96, 256, 0, stream>>>(x, xmean);
  k_sca <<<1, 256, 0, stream>>>(xmean, wsca, bsca, sca);
  k_pw1 <<<dim3(512, 2), 256, 0, stream>>>(x, w1a, b1a, w1c, b1c, ha, hc);
  k_dw  <<<12288, 256, 0, stream>>>(ha, hc, wdwa, bdwa, wdwc, bdwc, x1, uf);
  k_att <<<dim3(512, 2), 256, 0, stream>>>(x, wc2a, bc2a, wc2b, bc2b, w211, b211, attg, att);
  k_kba <<<dim3(512, 4), 256, 0, stream>>>(uf, x1, att, kbw, kbb, ga1, sca, y);
  k_proj<<<dim3(512, 2), 256, 0, stream>>>(y, wproj, bproj, out);
}

// Round 3
// 155.778 us; speedup vs baseline: 2.2815x; 1.3020x over previous
//
#include <hip/hip_runtime.h>
#include <math.h>

#define HW 16384
#define Wd 128

typedef __attribute__((ext_vector_type(8))) short short8;
typedef __attribute__((ext_vector_type(4))) float f32x4;

__device__ __forceinline__ unsigned short bf16r(float f) {
  unsigned int u = __float_as_uint(f);
  unsigned int r = (u + 0x7FFFu + ((u >> 16) & 1u)) >> 16;   // RNE
  return (unsigned short)r;
}

// ---------------- K1: per (b,c) spatial mean ----------------
__global__ void k_mean(const float* __restrict__ x, float* __restrict__ xmean) {
  int bc = blockIdx.x;                       // 0..95  (b*48+c)
  const float* p = x + (size_t)bc * HW;
  float s = 0.f;
  for (int i = threadIdx.x; i < HW; i += 256) s += p[i];
  #pragma unroll
  for (int off = 32; off > 0; off >>= 1) s += __shfl_down(s, off, 64);
  __shared__ float wsum[4];
  int lane = threadIdx.x & 63, wv = threadIdx.x >> 6;
  if (lane == 0) wsum[wv] = s;
  __syncthreads();
  if (threadIdx.x == 0)
    xmean[bc] = (wsum[0] + wsum[1] + wsum[2] + wsum[3]) * (1.f / 16384.f);
}

__global__ void k_sca(const float* __restrict__ xmean, const float* __restrict__ w_sca,
                      const float* __restrict__ b_sca, float* __restrict__ sca) {
  int t = threadIdx.x;
  if (t < 192) {
    int b = t / 96, co = t % 96;
    float acc = b_sca[co];
    for (int ci = 0; ci < 48; ci++) acc += w_sca[co * 48 + ci] * xmean[b * 48 + ci];
    sca[t] = acc;
  }
}

// ---------------- K3: two 1x1 convs 48->96 (h_a, h_c) ----------------
__global__ void k_pw1(const float* __restrict__ x,
                      const float* __restrict__ w1a, const float* __restrict__ b1a,
                      const float* __restrict__ w1c, const float* __restrict__ b1c,
                      float* __restrict__ ha, float* __restrict__ hc) {
  int lane = threadIdx.x & 63;
  int wv = __builtin_amdgcn_readfirstlane((int)(threadIdx.x >> 6));
  int slot = __builtin_amdgcn_readfirstlane((int)(blockIdx.y * 4 + wv));
  int p = blockIdx.x * 64 + lane;
  int b = p >> 14, sp = p & (HW - 1);
  const float* xb = x + (size_t)b * 48 * HW + sp;
  float xv[48];
  #pragma unroll
  for (int ci = 0; ci < 48; ci++) xv[ci] = xb[(size_t)ci * HW];
  float* hab = ha + (size_t)b * 96 * HW + sp;
  float* hcb = hc + (size_t)b * 96 * HW + sp;
  int c0 = slot * 12;
  for (int co = c0; co < c0 + 12; co++) {
    float aa = b1a[co], ac = b1c[co];
    const float* wa = w1a + co * 48;
    const float* wc = w1c + co * 48;
    #pragma unroll
    for (int ci = 0; ci < 48; ci++) { aa += wa[ci] * xv[ci]; ac += wc[ci] * xv[ci]; }
    hab[(size_t)co * HW] = aa;
    hcb[(size_t)co * HW] = ac;
  }
}

// ---------------- K4: depthwise 3x3 ----------------
__global__ void k_dw(const float* __restrict__ ha, const float* __restrict__ hc,
                     const float* __restrict__ wdwa, const float* __restrict__ bdwa,
                     const float* __restrict__ wdwc, const float* __restrict__ bdwc,
                     float* __restrict__ x1, float* __restrict__ uf) {
  int idx = blockIdx.x * 256 + threadIdx.x;        // < B*96*HW
  int sp = idx & (HW - 1);
  int bc = idx >> 14;                              // b*96+ch
  int ch = bc % 96;
  int r = sp >> 7, c = sp & 127;
  const float* pa = ha + (size_t)bc * HW;
  const float* pc = hc + (size_t)bc * HW;
  float aa = bdwa[ch], ac = bdwc[ch];
  #pragma unroll
  for (int t9 = 0; t9 < 9; t9++) {
    int rr = r + t9 / 3 - 1, cc = c + t9 % 3 - 1;
    bool ok = ((unsigned)rr < 128u) && ((unsigned)cc < 128u);
    float va = ok ? pa[rr * Wd + cc] : 0.f;
    float vc = ok ? pc[rr * Wd + cc] : 0.f;
    float wa = wdwa[ch * 9 + t9], wc = wdwc[ch * 9 + t9];
    aa += wa * va;
    ac += wc * vc;
  }
  x1[idx] = aa;
  uf[idx] = ac;
}

// ---------------- K5: att branch ----------------
__global__ void k_att(const float* __restrict__ x,
                      const float* __restrict__ wc2a, const float* __restrict__ bc2a,
                      const float* __restrict__ wc2b, const float* __restrict__ bc2b,
                      const float* __restrict__ w211, const float* __restrict__ b211,
                      const float* __restrict__ attg, float* __restrict__ att) {
  int lane = threadIdx.x & 63;
  int wv = __builtin_amdgcn_readfirstlane((int)(threadIdx.x >> 6));
  int slot = __builtin_amdgcn_readfirstlane((int)(blockIdx.y * 4 + wv));
  int p = blockIdx.x * 64 + lane;
  int b = p >> 14, sp = p & (HW - 1);
  int r = sp >> 7, c = sp & 127;
  const float* xb = x + (size_t)b * 48 * HW;
  float m[12];
  {
    float t[24];
    for (int o = 0; o < 24; o++) {
      float acc = bc2a[o];
      #pragma unroll
      for (int ic = 0; ic < 2; ic++) {
        const float* xc = xb + (size_t)(2 * o + ic) * HW;
        const float* wo = wc2a + o * 18 + ic * 9;
        #pragma unroll
        for (int t9 = 0; t9 < 9; t9++) {
          int rr = r + t9 / 3 - 1, cc = c + t9 % 3 - 1;
          float v = (((unsigned)rr < 128u) && ((unsigned)cc < 128u)) ? xc[rr * Wd + cc] : 0.f;
          acc += wo[t9] * v;
        }
      }
      t[o] = acc;
    }
    #pragma unroll
    for (int i = 0; i < 12; i++) m[i] = t[i] * t[i + 12];
  }
  float xv[48];
  #pragma unroll
  for (int ci = 0; ci < 48; ci++) xv[ci] = xb[(size_t)ci * HW + sp];
  float* ab = att + (size_t)b * 32 * HW + sp;
  int n0 = slot * 4;
  for (int n = n0; n < n0 + 4; n++) {
    float a1 = bc2b[n];
    #pragma unroll
    for (int i = 0; i < 12; i++) a1 += wc2b[n * 12 + i] * m[i];
    float a2 = b211[n];
    #pragma unroll
    for (int ci = 0; ci < 48; ci++) a2 += w211[n * 48 + ci] * xv[ci];
    ab[(size_t)n * HW] = a1 * attg[n] + a2;
  }
}

// ---------------- K_prep: repack kbw+kbb -> bf16 A-tile [48][64][32] ----------------
// kwA[g][nc][k]: nc=2n+i; k<18 -> kbw[n][g*36+i*18+k]; k==18 -> kbb[n][2g+i]; else 0
__global__ void k_prep(const float* __restrict__ kbw, const float* __restrict__ kbb,
                       unsigned short* __restrict__ kwA) {
  int e = blockIdx.x * 256 + threadIdx.x;          // < 48*64*32 = 98304
  int k = e & 31, nc = (e >> 5) & 63, g = e >> 11;
  int n = nc >> 1, i = nc & 1;
  float v = 0.f;
  if (k < 18) v = kbw[n * 1728 + g * 36 + i * 18 + k];
  else if (k == 18) v = kbb[n * 96 + 2 * g + i];
  kwA[e] = bf16r(v);
}

// ---------------- K6: fused kba via MFMA ----------------
// grid (512,4) x 256. Block = 64 px; wave wv owns px [wv*16, +16), groups gq*12..+11.
// Per group: T[nc][px] = mfma(kwA[g], P) over K=32 (18 taps + bias-slot + zeros),
// then out[px][c] = sum_n att[n][px]*T[2n+c][px] via per-lane FMA + hi-butterfly.
__global__ __launch_bounds__(256) void k_kba(
    const float* __restrict__ uf, const float* __restrict__ x1,
    const float* __restrict__ att, const unsigned short* __restrict__ kwA,
    const float* __restrict__ ga1, const float* __restrict__ sca,
    float* __restrict__ y) {
  int tid = threadIdx.x;
  int lane = tid & 63;
  int wv = tid >> 6;
  int lo = lane & 15, hi = lane >> 4;
  int bid = blockIdx.x;                            // 0..511
  int b = bid >> 8;
  int sp = ((bid & 255) << 6) + wv * 16 + lo;      // this lane's pixel
  int r = sp >> 7, c = sp & 127;
  int g0 = blockIdx.y * 12;

  const float* ufb  = uf  + (size_t)b * 96 * HW;
  const float* x1b  = x1  + (size_t)b * 96 * HW;
  const float* attb = att + (size_t)b * 32 * HW;
  float* yb = y + (size_t)b * 96 * HW;

  // att[n][sp] for this lane's 8 n-slots: n = 8*mt + 2*hi + q
  float attv[8];
  #pragma unroll
  for (int mt = 0; mt < 4; mt++)
    #pragma unroll
    for (int q = 0; q < 2; q++)
      attv[mt * 2 + q] = attb[(size_t)(8 * mt + 2 * hi + q) * HW + sp];

  // P-tap descriptors for this lane's 8 K-slots (jj = hi*8 + j2)
  int cha[8], off[8];
  bool ok[8];
  float dv[8];
  #pragma unroll
  for (int j2 = 0; j2 < 8; j2++) {
    int jj = hi * 8 + j2;
    if (jj < 18) {
      int ch = jj / 9, tap = jj % 9;
      int rr = r + tap / 3 - 1, cc = c + tap % 3 - 1;
      cha[j2] = ch;
      ok[j2] = ((unsigned)rr < 128u) && ((unsigned)cc < 128u);
      off[j2] = rr * Wd + cc;
      dv[j2] = 0.f;
    } else {
      cha[j2] = 0; ok[j2] = false; off[j2] = 0;
      dv[j2] = (jj == 18) ? 1.f : 0.f;             // bias slot
    }
  }

  for (int g = g0; g < g0 + 12; g++) {
    // B-frag: pack this lane's 8 P values (bf16 pairs, even k in low half)
    union { unsigned int u[4]; short8 s; } bfr;
    #pragma unroll
    for (int q = 0; q < 4; q++) {
      float v0 = ok[2 * q]     ? ufb[(size_t)(2 * g + cha[2 * q])     * HW + off[2 * q]]     : dv[2 * q];
      float v1 = ok[2 * q + 1] ? ufb[(size_t)(2 * g + cha[2 * q + 1]) * HW + off[2 * q + 1]] : dv[2 * q + 1];
      bfr.u[q] = (unsigned int)bf16r(v0) | ((unsigned int)bf16r(v1) << 16);
    }
    // A-frags + 4 MFMAs (one per 16 nc-rows)
    const unsigned short* kg = kwA + g * 2048;
    f32x4 acc[4];
    #pragma unroll
    for (int mt = 0; mt < 4; mt++) {
      short8 afr = *(const short8*)(kg + (16 * mt + lo) * 32 + hi * 8);
      f32x4 zero = {0.f, 0.f, 0.f, 0.f};
      acc[mt] = __builtin_amdgcn_mfma_f32_16x16x32_bf16(afr, bfr.s, zero, 0, 0, 0);
    }
    // reduce over n: D row nc = 16mt + hi*4 + reg; n = 8mt+2hi+(reg>>1); c = reg&1
    float s0 = 0.f, s1 = 0.f;
    #pragma unroll
    for (int mt = 0; mt < 4; mt++) {
      s0 += attv[mt * 2 + 0] * acc[mt][0] + attv[mt * 2 + 1] * acc[mt][2];
      s1 += attv[mt * 2 + 0] * acc[mt][1] + attv[mt * 2 + 1] * acc[mt][3];
    }
    s0 += __shfl_xor(s0, 16); s0 += __shfl_xor(s0, 32);
    s1 += __shfl_xor(s1, 16); s1 += __shfl_xor(s1, 32);
    // epilogue: ch = 2g+hi for hi<2
    if (hi < 2) {
      int ch = 2 * g + hi;
      float s = hi ? s1 : s0;
      float x2 = s * ga1[ch] + ufb[(size_t)ch * HW + sp];
      float v = x1b[(size_t)ch * HW + sp];
      float gl = v * 0.5f * (1.f + erff(v * 0.70710678118654752440f));
      yb[(size_t)ch * HW + sp] = gl * x2 * sca[b * 96 + ch];
    }
  }
}

// ---------------- K7: project_out 96->48 ----------------
__global__ void k_proj(const float* __restrict__ y, const float* __restrict__ wproj,
                       const float* __restrict__ bproj, float* __restrict__ out) {
  int lane = threadIdx.x & 63;
  int wv = __builtin_amdgcn_readfirstlane((int)(threadIdx.x >> 6));
  int slot = __builtin_amdgcn_readfirstlane((int)(blockIdx.y * 4 + wv));
  int p = blockIdx.x * 64 + lane;
  int b = p >> 14, sp = p & (HW - 1);
  const float* yb = y + (size_t)b * 96 * HW + sp;
  float yv[96];
  #pragma unroll
  for (int c = 0; c < 96; c++) yv[c] = yb[(size_t)c * HW];
  float* ob = out + (size_t)b * 48 * HW + sp;
  int co0 = slot * 6;
  for (int co = co0; co < co0 + 6; co++) {
    float acc = bproj[co];
    const float* w = wproj + co * 96;
    #pragma unroll
    for (int c = 0; c < 96; c++) acc += w[c] * yv[c];
    ob[(size_t)co * HW] = acc;
  }
}

extern "C" void kernel_launch(void* const* d_in, const int* in_sizes, int n_in,
                              void* d_out, int out_size, void* d_ws, size_t ws_size,
                              hipStream_t stream) {
  const float* x    = (const float*)d_in[0];
  const float* w1a  = (const float*)d_in[1];
  const float* b1a  = (const float*)d_in[2];
  const float* wdwa = (const float*)d_in[3];
  const float* bdwa = (const float*)d_in[4];
  const float* w1c  = (const float*)d_in[5];
  const float* b1c  = (const float*)d_in[6];
  const float* wdwc = (const float*)d_in[7];
  const float* bdwc = (const float*)d_in[8];
  const float* wsca = (const float*)d_in[9];
  const float* bsca = (const float*)d_in[10];
  const float* wc2a = (const float*)d_in[11];
  const float* bc2a = (const float*)d_in[12];
  const float* wc2b = (const float*)d_in[13];
  const float* bc2b = (const float*)d_in[14];
  const float* w211 = (const float*)d_in[15];
  const float* b211 = (const float*)d_in[16];
  const float* wproj= (const float*)d_in[17];
  const float* bproj= (const float*)d_in[18];
  const float* kbw  = (const float*)d_in[19];
  const float* kbb  = (const float*)d_in[20];
  const float* attg = (const float*)d_in[21];
  const float* ga1  = (const float*)d_in[22];
  float* out = (float*)d_out;

  float* ws    = (float*)d_ws;
  float* xmean = ws;                 // 96
  float* sca   = ws + 96;            // 192
  float* ha    = ws + 288;           // 3145728
  float* hc    = ha + 3145728;       // 3145728 (dead after k_dw)
  float* x1    = hc + 3145728;       // 3145728
  float* uf    = x1 + 3145728;       // 3145728
  float* att   = uf + 3145728;       // 1048576
  float* y     = ha;                              // reuse: ha dead after k_dw
  unsigned short* kwA = (unsigned short*)hc;      // reuse: hc dead after k_dw (98304 u16)

  k_mean<<<96, 256, 0, stream>>>(x, xmean);
  k_sca <<<1, 256, 0, stream>>>(xmean, wsca, bsca, sca);
  k_pw1 <<<dim3(512, 2), 256, 0, stream>>>(x, w1a, b1a, w1c, b1c, ha, hc);
  k_dw  <<<12288, 256, 0, stream>>>(ha, hc, wdwa, bdwa, wdwc, bdwc, x1, uf);
  k_prep<<<384, 256, 0, stream>>>(kbw, kbb, kwA);
  k_att <<<dim3(512, 2), 256, 0, stream>>>(x, wc2a, bc2a, wc2b, bc2b, w211, b211, attg, att);
  k_kba <<<dim3(512, 4), 256, 0, stream>>>(uf, x1, att, kwA, ga1, sca, y);
  k_proj<<<dim3(512, 2), 256, 0, stream>>>(y, wproj, bproj, out);
}

// Round 5
// 119.291 us; speedup vs baseline: 2.9793x; 1.3059x over previous
//
#include <hip/hip_runtime.h>
#include <math.h>

#define HW 16384
#define Wd 128

typedef __attribute__((ext_vector_type(8))) short short8;
typedef __attribute__((ext_vector_type(4))) float f32x4;

__device__ __forceinline__ unsigned short bf16r(float f) {
  unsigned int u = __float_as_uint(f);
  unsigned int r = (u + 0x7FFFu + ((u >> 16) & 1u)) >> 16;   // RNE
  return (unsigned short)r;
}

__device__ __forceinline__ unsigned cvt_pk_bf16(float a, float b) {
  unsigned r;
  asm("v_cvt_pk_bf16_f32 %0, %1, %2" : "=v"(r) : "v"(a), "v"(b));
  return r;
}

// ---------------- K1: per (b,c) spatial mean ----------------
__global__ void k_mean(const float* __restrict__ x, float* __restrict__ xmean) {
  int bc = blockIdx.x;                       // 0..95  (b*48+c)
  const float* p = x + (size_t)bc * HW;
  float s = 0.f;
  for (int i = threadIdx.x; i < HW; i += 256) s += p[i];
  #pragma unroll
  for (int off = 32; off > 0; off >>= 1) s += __shfl_down(s, off, 64);
  __shared__ float wsum[4];
  int lane = threadIdx.x & 63, wv = threadIdx.x >> 6;
  if (lane == 0) wsum[wv] = s;
  __syncthreads();
  if (threadIdx.x == 0)
    xmean[bc] = (wsum[0] + wsum[1] + wsum[2] + wsum[3]) * (1.f / 16384.f);
}

__global__ void k_sca(const float* __restrict__ xmean, const float* __restrict__ w_sca,
                      const float* __restrict__ b_sca, float* __restrict__ sca) {
  int t = threadIdx.x;
  if (t < 192) {
    int b = t / 96, co = t % 96;
    float acc = b_sca[co];
    for (int ci = 0; ci < 48; ci++) acc += w_sca[co * 48 + ci] * xmean[b * 48 + ci];
    sca[t] = acc;
  }
}

// ---------------- K3: two 1x1 convs 48->96 (h_a, h_c) ----------------
// grid (512,4): 64 px per block; slot handles 6 out-channels
__global__ void k_pw1(const float* __restrict__ x,
                      const float* __restrict__ w1a, const float* __restrict__ b1a,
                      const float* __restrict__ w1c, const float* __restrict__ b1c,
                      float* __restrict__ ha, float* __restrict__ hc) {
  int lane = threadIdx.x & 63;
  int wv = __builtin_amdgcn_readfirstlane((int)(threadIdx.x >> 6));
  int slot = __builtin_amdgcn_readfirstlane((int)(blockIdx.y * 4 + wv));
  int p = blockIdx.x * 64 + lane;
  int b = p >> 14, sp = p & (HW - 1);
  const float* xb = x + (size_t)b * 48 * HW + sp;
  float xv[48];
  #pragma unroll
  for (int ci = 0; ci < 48; ci++) xv[ci] = xb[(size_t)ci * HW];
  float* hab = ha + (size_t)b * 96 * HW + sp;
  float* hcb = hc + (size_t)b * 96 * HW + sp;
  int c0 = slot * 6;
  for (int co = c0; co < c0 + 6; co++) {
    float aa = b1a[co], ac = b1c[co];
    const float* wa = w1a + co * 48;
    const float* wc = w1c + co * 48;
    #pragma unroll
    for (int ci = 0; ci < 48; ci++) { aa += wa[ci] * xv[ci]; ac += wc[ci] * xv[ci]; }
    hab[(size_t)co * HW] = aa;
    hcb[(size_t)co * HW] = ac;
  }
}

// ---------------- K4: depthwise 3x3; x1 path gets gelu*sca folded in ----------------
__global__ void k_dw(const float* __restrict__ ha, const float* __restrict__ hc,
                     const float* __restrict__ wdwa, const float* __restrict__ bdwa,
                     const float* __restrict__ wdwc, const float* __restrict__ bdwc,
                     const float* __restrict__ sca,
                     float* __restrict__ x1g, float* __restrict__ uf) {
  int idx = blockIdx.x * 256 + threadIdx.x;        // < B*96*HW
  int sp = idx & (HW - 1);
  int bc = idx >> 14;                              // b*96+ch
  int ch = bc % 96;
  int r = sp >> 7, c = sp & 127;
  const float* pa = ha + (size_t)bc * HW;
  const float* pc = hc + (size_t)bc * HW;
  float aa = bdwa[ch], ac = bdwc[ch];
  #pragma unroll
  for (int t9 = 0; t9 < 9; t9++) {
    int rr = r + t9 / 3 - 1, cc = c + t9 % 3 - 1;
    bool ok = ((unsigned)rr < 128u) && ((unsigned)cc < 128u);
    float va = ok ? pa[rr * Wd + cc] : 0.f;
    float vc = ok ? pc[rr * Wd + cc] : 0.f;
    aa += wdwa[ch * 9 + t9] * va;
    ac += wdwc[ch * 9 + t9] * vc;
  }
  float gl = aa * 0.5f * (1.f + erff(aa * 0.70710678118654752440f));
  x1g[idx] = gl * sca[bc];
  uf[idx] = ac;
}

// ---------------- K5a: gate m = t1*t2 (grouped 3x3 + SimpleGate) ----------------
// one thread per (b, i<12, sp)
__global__ void k_gate(const float* __restrict__ x, const float* __restrict__ wc2a,
                       const float* __restrict__ bc2a, float* __restrict__ m) {
  int idx = blockIdx.x * 256 + threadIdx.x;        // < B*12*HW = 393216
  int sp = idx & (HW - 1);
  int bi = idx >> 14;                              // b*12+i
  int i = bi % 12, b = bi / 12;
  int r = sp >> 7, c = sp & 127;
  const float* xb = x + (size_t)b * 48 * HW;
  float t[2];
  #pragma unroll
  for (int half = 0; half < 2; half++) {
    int o = i + half * 12;
    float acc = bc2a[o];
    #pragma unroll
    for (int ic = 0; ic < 2; ic++) {
      const float* xc = xb + (size_t)(2 * o + ic) * HW;
      const float* wo = wc2a + o * 18 + ic * 9;
      #pragma unroll
      for (int t9 = 0; t9 < 9; t9++) {
        int rr = r + t9 / 3 - 1, cc = c + t9 % 3 - 1;
        float v = (((unsigned)rr < 128u) && ((unsigned)cc < 128u)) ? xc[rr * Wd + cc] : 0.f;
        acc += wo[t9] * v;
      }
    }
    t[half] = acc;
  }
  m[idx] = t[0] * t[1];
}

// ---------------- K5b: att = 1x1(m)*gamma + 1x1(x) ----------------
// grid (512,2): slot handles 4 att channels
__global__ void k_att2(const float* __restrict__ x, const float* __restrict__ m,
                       const float* __restrict__ wc2b, const float* __restrict__ bc2b,
                       const float* __restrict__ w211, const float* __restrict__ b211,
                       const float* __restrict__ attg, float* __restrict__ att) {
  int lane = threadIdx.x & 63;
  int wv = __builtin_amdgcn_readfirstlane((int)(threadIdx.x >> 6));
  int slot = __builtin_amdgcn_readfirstlane((int)(blockIdx.y * 4 + wv));
  int p = blockIdx.x * 64 + lane;
  int b = p >> 14, sp = p & (HW - 1);
  float mv[12];
  const float* mb = m + (size_t)b * 12 * HW + sp;
  #pragma unroll
  for (int i = 0; i < 12; i++) mv[i] = mb[(size_t)i * HW];
  float xv[48];
  const float* xb = x + (size_t)b * 48 * HW + sp;
  #pragma unroll
  for (int ci = 0; ci < 48; ci++) xv[ci] = xb[(size_t)ci * HW];
  float* ab = att + (size_t)b * 32 * HW + sp;
  int n0 = slot * 4;
  for (int n = n0; n < n0 + 4; n++) {
    float a1 = bc2b[n];
    #pragma unroll
    for (int i = 0; i < 12; i++) a1 += wc2b[n * 12 + i] * mv[i];
    float a2 = b211[n];
    #pragma unroll
    for (int ci = 0; ci < 48; ci++) a2 += w211[n * 48 + ci] * xv[ci];
    ab[(size_t)n * HW] = a1 * attg[n] + a2;
  }
}

// ---------------- K_prep: repack kbw+kbb -> bf16 A-tile [48][64][32] ----------------
// K-slot map (center-aligned; q = k>>3, j2 = k&7):
//   q0: j2<5 -> jj = j2        (ch0 taps 0-4; center jj=4 at j2=4)
//   q1: j2<5 -> jj = 9+j2      (ch1 taps 0-4; center jj=13 at j2=4)
//   q2: j2<4 -> jj = 5+j2      (ch0 taps 5-8)
//   q3: j2<4 -> jj = 14+j2     (ch1 taps 5-8); j2==4 -> bias
// jj<18 carries weight index i*18+jj (input-ch jj/9, tap jj%9); rest zero.
__global__ void k_prep(const float* __restrict__ kbw, const float* __restrict__ kbb,
                       unsigned short* __restrict__ kwA) {
  int e = blockIdx.x * 256 + threadIdx.x;          // < 48*64*32 = 98304
  int k = e & 31, nc = (e >> 5) & 63, g = e >> 11;
  int n = nc >> 1, i = nc & 1;
  int q = k >> 3, j2 = k & 7;
  float v = 0.f;
  int jj = -1;
  if (q == 0)      { if (j2 < 5) jj = j2; }
  else if (q == 1) { if (j2 < 5) jj = 9 + j2; }
  else if (q == 2) { if (j2 < 4) jj = 5 + j2; }
  else             { if (j2 < 4) jj = 14 + j2; else if (j2 == 4) v = kbb[n * 96 + 2 * g + i]; }
  if (jj >= 0) v = kbw[n * 1728 + g * 36 + i * 18 + jj];
  kwA[e] = bf16r(v);
}

// ---------------- K6: fused kba via MFMA ----------------
// grid (512,4) x 256. Wave wv owns px [wv*16,+16); block covers groups gq*12..+11.
__global__ __launch_bounds__(256) void k_kba(
    const float* __restrict__ uf, const float* __restrict__ x1g,
    const float* __restrict__ att, const unsigned short* __restrict__ kwA,
    const float* __restrict__ ga1, float* __restrict__ y) {
  int tid = threadIdx.x;
  int lane = tid & 63;
  int wv = tid >> 6;
  int lo = lane & 15, hi = lane >> 4;
  int bid = blockIdx.x;                            // 0..511
  int b = bid >> 8;
  int sp = ((bid & 255) << 6) + wv * 16 + lo;      // this lane's pixel
  int r = sp >> 7, c = sp & 127;
  int g0 = blockIdx.y * 12;

  const float* ufb  = uf  + (size_t)b * 96 * HW;
  const float* x1gb = x1g + (size_t)b * 96 * HW;
  const float* attb = att + (size_t)b * 32 * HW;
  float* yb = y + (size_t)b * 96 * HW;

  // att[n][sp] for this lane's 8 n-slots: n = 8*mt + 2*hi + q
  float attv[8];
  #pragma unroll
  for (int mt = 0; mt < 4; mt++)
    #pragma unroll
    for (int q = 0; q < 2; q++)
      attv[mt * 2 + q] = attb[(size_t)(8 * mt + 2 * hi + q) * HW + sp];

  // tap descriptors for this lane's 5 K-slots (center-aligned map, must
  // match k_prep exactly; the shared permutation cancels inside the MFMA)
  const float* pj[5];
  bool ok[5];
  float dv[5];
  #pragma unroll
  for (int j2 = 0; j2 < 5; j2++) {
    int jj = (hi == 0) ? j2 : (hi == 1) ? 9 + j2 : (hi == 2) ? 5 + j2 : 14 + j2;
    bool real = (hi < 2) || (j2 < 4);
    if (real) {
      int ch = jj / 9, tap = jj % 9;
      int rr = r + tap / 3 - 1, cc = c + tap % 3 - 1;
      bool inb = ((unsigned)rr < 128u) && ((unsigned)cc < 128u);
      ok[j2] = inb;
      dv[j2] = 0.f;
      pj[j2] = ufb + (size_t)(2 * g0 + ch) * HW + (inb ? rr * Wd + cc : 0);
    } else {
      ok[j2] = false;
      dv[j2] = (hi == 3) ? 1.f : 0.f;              // bias slot (q3, j2==4)
      pj[j2] = ufb;
    }
  }

  for (int g = g0; g < g0 + 12; g++) {
    float v[5];
    #pragma unroll
    for (int j2 = 0; j2 < 5; j2++) v[j2] = ok[j2] ? pj[j2][0] : dv[j2];
    union { unsigned u[4]; short8 s; } bfr;
    bfr.u[0] = cvt_pk_bf16(v[0], v[1]);
    bfr.u[1] = cvt_pk_bf16(v[2], v[3]);
    bfr.u[2] = cvt_pk_bf16(v[4], 0.f);
    bfr.u[3] = 0u;

    const unsigned short* kg = kwA + g * 2048;
    f32x4 acc[4];
    #pragma unroll
    for (int mt = 0; mt < 4; mt++) {
      short8 afr = *(const short8*)(kg + (16 * mt + lo) * 32 + hi * 8);
      f32x4 zero = {0.f, 0.f, 0.f, 0.f};
      acc[mt] = __builtin_amdgcn_mfma_f32_16x16x32_bf16(afr, bfr.s, zero, 0, 0, 0);
    }
    // reduce over n: D row nc = 16mt + hi*4 + reg; n = 8mt+2hi+(reg>>1); c = reg&1
    float s0 = 0.f, s1 = 0.f;
    #pragma unroll
    for (int mt = 0; mt < 4; mt++) {
      s0 += attv[mt * 2 + 0] * acc[mt][0] + attv[mt * 2 + 1] * acc[mt][2];
      s1 += attv[mt * 2 + 0] * acc[mt][1] + attv[mt * 2 + 1] * acc[mt][3];
    }
    s0 += __shfl_xor(s0, 16); s0 += __shfl_xor(s0, 32);
    s1 += __shfl_xor(s1, 16); s1 += __shfl_xor(s1, 32);
    // epilogue: lane quarter hi<2 writes ch = 2g+hi; its own center tap is v[4]
    // (hi=0: jj=4 = ch0 center; hi=1: jj=13 = ch1 center)
    if (hi < 2) {
      int ch = 2 * g + hi;
      float s = hi ? s1 : s0;
      float x2 = s * ga1[ch] + v[4];
      yb[(size_t)ch * HW + sp] = x1gb[(size_t)ch * HW + sp] * x2;
    }
    #pragma unroll
    for (int j2 = 0; j2 < 5; j2++) pj[j2] += 2 * HW;
  }
}

// ---------------- K7: project_out 96->48 ----------------
__global__ void k_proj(const float* __restrict__ y, const float* __restrict__ wproj,
                       const float* __restrict__ bproj, float* __restrict__ out) {
  int lane = threadIdx.x & 63;
  int wv = __builtin_amdgcn_readfirstlane((int)(threadIdx.x >> 6));
  int slot = __builtin_amdgcn_readfirstlane((int)(blockIdx.y * 4 + wv));
  int p = blockIdx.x * 64 + lane;
  int b = p >> 14, sp = p & (HW - 1);
  const float* yb = y + (size_t)b * 96 * HW + sp;
  float yv[96];
  #pragma unroll
  for (int c = 0; c < 96; c++) yv[c] = yb[(size_t)c * HW];
  float* ob = out + (size_t)b * 48 * HW + sp;
  int co0 = slot * 6;
  for (int co = co0; co < co0 + 6; co++) {
    float acc = bproj[co];
    const float* w = wproj + co * 96;
    #pragma unroll
    for (int c = 0; c < 96; c++) acc += w[c] * yv[c];
    ob[(size_t)co * HW] = acc;
  }
}

extern "C" void kernel_launch(void* const* d_in, const int* in_sizes, int n_in,
                              void* d_out, int out_size, void* d_ws, size_t ws_size,
                              hipStream_t stream) {
  const float* x    = (const float*)d_in[0];
  const float* w1a  = (const float*)d_in[1];
  const float* b1a  = (const float*)d_in[2];
  const float* wdwa = (const float*)d_in[3];
  const float* bdwa = (const float*)d_in[4];
  const float* w1c  = (const float*)d_in[5];
  const float* b1c  = (const float*)d_in[6];
  const float* wdwc = (const float*)d_in[7];
  const float* bdwc = (const float*)d_in[8];
  const float* wsca = (const float*)d_in[9];
  const float* bsca = (const float*)d_in[10];
  const float* wc2a = (const float*)d_in[11];
  const float* bc2a = (const float*)d_in[12];
  const float* wc2b = (const float*)d_in[13];
  const float* bc2b = (const float*)d_in[14];
  const float* w211 = (const float*)d_in[15];
  const float* b211 = (const float*)d_in[16];
  const float* wproj= (const float*)d_in[17];
  const float* bproj= (const float*)d_in[18];
  const float* kbw  = (const float*)d_in[19];
  const float* kbb  = (const float*)d_in[20];
  const float* attg = (const float*)d_in[21];
  const float* ga1  = (const float*)d_in[22];
  float* out = (float*)d_out;

  float* ws    = (float*)d_ws;
  float* xmean = ws;                 // 96
  float* sca   = ws + 96;            // 192
  float* ha    = ws + 288;           // 3145728 (later: m, then y)
  float* hc    = ha + 3145728;       // 3145728 (later: kwA)
  float* x1g   = hc + 3145728;       // 3145728
  float* uf    = x1g + 3145728;      // 3145728
  float* att   = uf + 3145728;       // 1048576
  float* y     = ha;                              // ha dead after k_dw
  float* m     = ha;                              // m lifetime [k_gate, k_att2] < y's
  unsigned short* kwA = (unsigned short*)hc;      // hc dead after k_dw

  k_mean<<<96, 256, 0, stream>>>(x, xmean);
  k_sca <<<1, 256, 0, stream>>>(xmean, wsca, bsca, sca);
  k_pw1 <<<dim3(512, 4), 256, 0, stream>>>(x, w1a, b1a, w1c, b1c, ha, hc);
  k_dw  <<<12288, 256, 0, stream>>>(ha, hc, wdwa, bdwa, wdwc, bdwc, sca, x1g, uf);
  k_prep<<<384, 256, 0, stream>>>(kbw, kbb, kwA);
  k_gate<<<1536, 256, 0, stream>>>(x, wc2a, bc2a, m);
  k_att2<<<dim3(512, 2), 256, 0, stream>>>(x, m, wc2b, bc2b, w211, b211, attg, att);
  k_kba <<<dim3(512, 4), 256, 0, stream>>>(uf, x1g, att, kwA, ga1, y);
  k_proj<<<dim3(512, 2), 256, 0, stream>>>(y, wproj, bproj, out);
}